// Round 12
// baseline (260.129 us; speedup 1.0000x reference)
//
#include <hip/hip_runtime.h>
#include <stdint.h>

#define HW   1369      // 37*37 output pixels
#define QW   39        // padded row width
#define QP   1616      // padded plane rows per (b) in Xp
#define QT   1536      // q rows in x1 (per batch)
#define CIN  1024
#define CMID 512
#define KTOT 9216      // 9 * 1024
#define NTIL 144       // K-tiles: 16 cblocks(64) * 9 taps, cblock-major tap-inner
#define ASL  12288     // A slot stride (elements): 192 x 64 (24 KB)

typedef float  f32x4  __attribute__((ext_vector_type(4)));
typedef __bf16 bf16x8 __attribute__((ext_vector_type(8)));

__device__ __forceinline__ uint16_t f2bf(float f) {
  uint32_t u = __float_as_uint(f);
  u += 0x7fffu + ((u >> 16) & 1u);
  return (uint16_t)(u >> 16);
}

// global -> LDS direct copy, 16B per lane. LDS dest = wave-uniform base + lane*16.
__device__ __forceinline__ void gll16(const void* g, void* l) {
  const __attribute__((address_space(1))) uint32_t* ga =
      (const __attribute__((address_space(1))) uint32_t*)(uintptr_t)g;
  __attribute__((address_space(3))) uint32_t* la =
      (__attribute__((address_space(3))) uint32_t*)(uint32_t)(uintptr_t)l;
  __builtin_amdgcn_global_load_lds(ga, la, 16, 0, 0);
}

// ---------- prep: fmap [b][c][h][w] f32 -> Xp [b][q][c] bf16 (padded, zeroed border) ----------
__global__ void k_pad_transpose(const float* __restrict__ fmap, uint16_t* __restrict__ Xp) {
  __shared__ float t[32][33];
  const int b = blockIdx.z;
  const int c0 = blockIdx.y * 32;
  const int p0 = blockIdx.x * 32;
  const int tx = threadIdx.x, ty = threadIdx.y;
  const float* src = fmap + ((size_t)b * CIN + c0) * HW + p0;
#pragma unroll
  for (int i = 0; i < 4; ++i) {
    int cc = ty + i * 8;
    t[cc][tx] = (p0 + tx < HW) ? src[(size_t)cc * HW + tx] : 0.f;
  }
  __syncthreads();
#pragma unroll
  for (int i = 0; i < 4; ++i) {
    int pl = ty + i * 8;
    int p = p0 + pl;
    if (p < HW) {
      int h = p / 37, w = p - h * 37;
      int q = (h + 1) * QW + (w + 1);
      Xp[((size_t)b * QP + q) * CIN + c0 + tx] = f2bf(t[tx][pl]);
    }
  }
}

// ---------- prep: W1 -> B fragments in MFMA order ----------
// Bp[frag][lane][8el], frag = (t*32 + o16)*2 + kk. Lane l of frag holds
// B[o16*16 + (l&15)][tap*1024 + cb*64 + kk*32 + (l>>4)*8 ..+8], t = cb*9+tap.
// A wave's frag load = 64 lanes x 16B CONTIGUOUS (1KB burst, VMEM pipe).
__global__ void k_pack_bfrag(const float* __restrict__ W1, uint16_t* __restrict__ Bp) {
  const int gid = blockIdx.x * 256 + threadIdx.x;   // 144*32*2*64 = 589824 exact
  const int lane = gid & 63;
  const int f    = gid >> 6;
  const int kk   = f & 1;
  const int o16  = (f >> 1) & 31;
  const int t    = f >> 6;
  const int cb = t / 9, tap = t - cb * 9;
  const int o   = o16 * 16 + (lane & 15);
  const int kap = kk * 32 + (lane >> 4) * 8;
  uint16_t* dst = Bp + (size_t)gid * 8;
#pragma unroll
  for (int e = 0; e < 8; ++e) {
    const int c = cb * 64 + kap + e;
    dst[e] = f2bf(W1[((size_t)o * CIN + c) * 9 + tap]);
  }
}

// ---------- prep: W2 [120][512] f32 -> W2p [128][512] bf16 ----------
__global__ void k_pack_w2(const float* __restrict__ W2, uint16_t* __restrict__ W2p) {
  int idx = blockIdx.x * 256 + threadIdx.x;
  int j = idx >> 9, o = idx & 511;
  W2p[idx] = (j < 120) ? f2bf(W2[j * 512 + o]) : (uint16_t)0;
}

// ---------- conv1: implicit GEMM, A via LDS, B via coalesced frag loads ----------
// Block = BM192 x BN128 x BK64, 4 waves (2M x 2N, wave 96x64), LDS 48KB
// (A only, 2x24KB). Grid = 512 = 2 blocks/CU (cross-block pipe overlap, r11).
// B: pre-packed fragments, wave reads 8 x 1KB contiguous bursts/tile on the
// VMEM pipe (register ping-pong bvX/bvY, prefetched t+1). Removes 96KB/CU of
// LDS traffic per tile-step -> LDS 144KB (1694cyc) < MFMA (1862cyc).
// One vmcnt(0)+barrier per tile (covers A-gll AND B loads). T2 XOR swizzle on A.
__global__ __launch_bounds__(256, 2) void k_conv1(
    const uint16_t* __restrict__ Xp, const uint16_t* __restrict__ Bp,
    const float* __restrict__ b1, uint16_t* __restrict__ x1) {
  __shared__ __align__(16) uint16_t lds[2 * ASL];   // 49152 B

  const int tid  = threadIdx.x;
  const int wid  = tid >> 6, lane = tid & 63;
  const int lrow = lane & 15, lq = lane >> 4;
  const int wm   = wid >> 1,  wn = wid & 1;           // 2M x 2N

  // grid: 512 blocks = 8 XCDs x 64, mt-major within XCD (4 nt consecutive)
  const int bid = blockIdx.x;
  const int g   = (bid & 7) * 64 + (bid >> 3);
  const int mt  = g >> 2, nt = g & 3;
  const int batch = mt >> 3, qb = (mt & 7) * 192;
  const int o0 = nt * 128;
  const uint16_t* Xb = Xp + (size_t)batch * QP * CIN;

  // A fragment-read swizzled cols (elements); lds_byte = glob_byte ^ ((row&7)<<4)
  const int xorb    = (lrow & 7) << 4;
  const int col_el0 = ((lq * 16) ^ xorb) >> 1;   // kk=0
  const int col_el1 = col_el0 ^ 32;              // kk=1 (toggle byte bit 6)

  // A staging: srow = tid>>3 (0..31), pre-swizzled source column
  const int scol = ((tid & 7) ^ ((tid >> 3) & 7)) * 8;   // elements
  const int srow = tid >> 3;

  // B frag pointers: per-lane base + frag index
  const uint16_t* Bpl = Bp + (size_t)lane * 8;
  const int o16b = nt * 8 + wn * 4;   // wave's first o16

  f32x4 acc[6][4] = {};

#define STAGEA(u) do {                                                                \
    if ((u) < NTIL) {                                                                 \
      const int cb_  = (u) / 9;                                                       \
      const int tap_ = (u) - cb_ * 9;                                                 \
      const int off_ = (tap_ / 3) * QW + tap_ % 3;                                    \
      const int c0_  = cb_ << 6;                                                      \
      uint16_t* sa = lds + ((u) & 1) * ASL;                                           \
      _Pragma("unroll")                                                               \
      for (int j = 0; j < 6; ++j)                                                     \
        gll16(Xb + (size_t)(qb + off_ + j * 32 + srow) * CIN + c0_ + scol,            \
              sa + (j * 256 + wid * 64) * 8);                                         \
    }                                                                                 \
  } while (0)

#define LOADB(u, BV) do {                                                             \
    if ((u) < NTIL) {                                                                 \
      _Pragma("unroll")                                                               \
      for (int n = 0; n < 4; ++n)                                                     \
        _Pragma("unroll")                                                             \
        for (int kk = 0; kk < 2; ++kk)                                                \
          BV[n * 2 + kk] = *(const bf16x8*)(                                          \
              Bpl + (((size_t)(u) * 32 + o16b + n) * 2 + kk) * 512);                  \
    }                                                                                 \
  } while (0)

  // TILE: consume B regs BVC (tile t), prefetch BVN (t+1), stage A(t+1)
#define TILE(t, BVC, BVN) do {                                                        \
    const uint16_t* As = lds + ((t) & 1) * ASL;                                       \
    asm volatile("s_waitcnt vmcnt(0)" ::: "memory");   /* A(t) in LDS, B(t) in regs */\
    asm volatile("s_barrier" ::: "memory");                                           \
    __builtin_amdgcn_sched_barrier(0);                                                \
    STAGEA((t) + 1);                                                                  \
    LOADB((t) + 1, BVN);                                                              \
    bf16x8 av0[6], av1[6];                                                            \
    _Pragma("unroll")                                                                 \
    for (int m = 0; m < 6; ++m) {                                                     \
      const uint16_t* ar = As + (wm * 96 + m * 16 + lrow) * 64;                       \
      av0[m] = *(const bf16x8*)(ar + col_el0);                                        \
      av1[m] = *(const bf16x8*)(ar + col_el1);                                        \
    }                                                                                 \
    __builtin_amdgcn_s_setprio(1);                                                    \
    _Pragma("unroll")                                                                 \
    for (int m = 0; m < 6; ++m)                                                       \
      _Pragma("unroll")                                                               \
      for (int n = 0; n < 4; ++n)                                                     \
        acc[m][n] = __builtin_amdgcn_mfma_f32_16x16x32_bf16(                          \
            av0[m], BVC[n * 2], acc[m][n], 0, 0, 0);                                  \
    _Pragma("unroll")                                                                 \
    for (int m = 0; m < 6; ++m)                                                       \
      _Pragma("unroll")                                                               \
      for (int n = 0; n < 4; ++n)                                                     \
        acc[m][n] = __builtin_amdgcn_mfma_f32_16x16x32_bf16(                          \
            av1[m], BVC[n * 2 + 1], acc[m][n], 0, 0, 0);                              \
    __builtin_amdgcn_s_setprio(0);                                                    \
  } while (0)

  // prologue: B(0) regs + A(0) staged; tile-0 vmcnt(0) drains both
  bf16x8 bvX[8], bvY[8];
  LOADB(0, bvX);
  STAGEA(0);

  for (int t = 0; t < NTIL; t += 2) {   // NTIL even; LOADB/STAGEA self-skip at 144
    TILE(t,     bvX, bvY);
    TILE(t + 1, bvY, bvX);
  }

  // epilogue: bias + ReLU6 -> x1 bf16
  const int qr = lq * 4;
#pragma unroll
  for (int n = 0; n < 4; ++n) {
    const int o = o0 + wn * 64 + n * 16 + lrow;
    const float bias = b1[o];
#pragma unroll
    for (int m = 0; m < 6; ++m) {
#pragma unroll
      for (int v = 0; v < 4; ++v) {
        const int q = qb + wm * 96 + m * 16 + qr + v;
        float x = acc[m][n][v] + bias;
        x = fminf(fmaxf(x, 0.f), 6.f);
        x1[((size_t)batch * QT + q) * CMID + o] = f2bf(x);
      }
    }
  }
#undef TILE
#undef LOADB
#undef STAGEA
}

// ---------- conv2: out[b][h][w][j] = sum_o x1[q][o] * W2[j][o] + b2[j] ----------
__global__ __launch_bounds__(256, 2) void k_conv2(
    const uint16_t* __restrict__ x1, const uint16_t* __restrict__ W2p,
    const float* __restrict__ b2, float* __restrict__ out) {
  __shared__ __align__(16) uint16_t lA[128 * 64];
  __shared__ __align__(16) uint16_t lB[128 * 64];
  const int tid = threadIdx.x;
  const int wid = tid >> 6, lane = tid & 63;
  const int b = blockIdx.z, q0 = blockIdx.x * 128;
  const uint16_t* Ab = x1 + (size_t)b * QT * CMID;
  const int wm = wid >> 1, wn = wid & 1;
  const int lrow = lane & 15, lk = (lane >> 4) * 8;
  f32x4 acc[4][4] = {};

  for (int kt = 0; kt < 8; ++kt) {
    const int c0 = kt << 6;
#pragma unroll
    for (int i = 0; i < 4; ++i) {
      int wb = i * 256 + wid * 64;
      int chunk = wb + lane;
      int row = chunk >> 3, ch = chunk & 7;
      gll16(Ab + (size_t)(q0 + row) * CMID + c0 + ch * 8, lA + wb * 8);
      gll16(W2p + (size_t)row * CMID + c0 + ch * 8, lB + wb * 8);
    }
    __syncthreads();
#pragma unroll
    for (int kk = 0; kk < 2; ++kk) {
      bf16x8 av[4], bv[4];
#pragma unroll
      for (int mi = 0; mi < 4; ++mi)
        av[mi] = *(const bf16x8*)(lA + (wm * 64 + mi * 16 + lrow) * 64 + kk * 32 + lk);
#pragma unroll
      for (int ni = 0; ni < 4; ++ni)
        bv[ni] = *(const bf16x8*)(lB + (wn * 64 + ni * 16 + lrow) * 64 + kk * 32 + lk);
#pragma unroll
      for (int mi = 0; mi < 4; ++mi)
#pragma unroll
        for (int ni = 0; ni < 4; ++ni)
          acc[mi][ni] = __builtin_amdgcn_mfma_f32_16x16x32_bf16(av[mi], bv[ni], acc[mi][ni], 0, 0, 0);
    }
    __syncthreads();
  }

  const int qr = (lane >> 4) * 4;
#pragma unroll
  for (int ni = 0; ni < 4; ++ni) {
    int j = wn * 64 + ni * 16 + lrow;
    if (j < 120) {
      float bias = b2[j];
#pragma unroll
      for (int mi = 0; mi < 4; ++mi) {
#pragma unroll
        for (int v = 0; v < 4; ++v) {
          int q = q0 + wm * 64 + mi * 16 + qr + v;
          int h = q / QW, w = q - h * QW;
          if (h < 37 && w < 37) {
            out[((size_t)b * HW + h * 37 + w) * 120 + j] = acc[mi][ni][v] + bias;
          }
        }
      }
    }
  }
}

extern "C" void kernel_launch(void* const* d_in, const int* in_sizes, int n_in,
                              void* d_out, int out_size, void* d_ws, size_t ws_size,
                              hipStream_t stream) {
  const float* fmap = (const float*)d_in[0];
  const float* W1   = (const float*)d_in[1];
  const float* b1   = (const float*)d_in[2];
  const float* W2   = (const float*)d_in[3];
  const float* b2   = (const float*)d_in[4];
  float* out = (float*)d_out;

  uint8_t* ws = (uint8_t*)d_ws;
  const size_t XP_BYTES = (size_t)16 * QP * CIN * 2;   // 52,953,088
  const size_t BP_BYTES = (size_t)144 * 32 * 2 * 64 * 8 * 2;   // 9,437,184
  const size_t W2P_BYTES = (size_t)128 * 512 * 2;      //    131,072
  uint16_t* Xp  = (uint16_t*)ws;
  uint16_t* Bp  = (uint16_t*)(ws + XP_BYTES);
  uint16_t* W2p = (uint16_t*)(ws + XP_BYTES + BP_BYTES);
  uint16_t* x1  = (uint16_t*)(ws + XP_BYTES + BP_BYTES + W2P_BYTES);

  hipMemsetAsync(Xp, 0, XP_BYTES, stream);
  k_pad_transpose<<<dim3(43, 32, 16), dim3(32, 8), 0, stream>>>(fmap, Xp);
  k_pack_bfrag<<<dim3(2304), dim3(256), 0, stream>>>(W1, Bp);
  k_pack_w2<<<dim3(256), dim3(256), 0, stream>>>(W2, W2p);
  k_conv1<<<dim3(512), dim3(256), 0, stream>>>(Xp, Bp, b1, x1);
  k_conv2<<<dim3(12, 1, 16), dim3(256), 0, stream>>>(x1, W2p, b2, out);
}